// Round 10
// baseline (171.614 us; speedup 1.0000x reference)
//
#include <hip/hip_runtime.h>
#include <hip/hip_bf16.h>

typedef __bf16 bf16;
typedef __bf16 bf16x8 __attribute__((ext_vector_type(8)));
typedef __bf16 bf16x4 __attribute__((ext_vector_type(4)));
typedef float f32x4 __attribute__((ext_vector_type(4)));

static __device__ __forceinline__ f32x4 mfma16(bf16x8 a, bf16x8 b, f32x4 c) {
  return __builtin_amdgcn_mfma_f32_16x16x32_bf16(a, b, c, 0, 0, 0);
}

// No-drain workgroup barrier (r5: neutral vs __syncthreads, kept).
static __device__ __forceinline__ void wg_barrier() {
  asm volatile("s_waitcnt lgkmcnt(0)" ::: "memory");
  __builtin_amdgcn_s_barrier();
  asm volatile("" ::: "memory");
}

static __device__ __forceinline__ bf16x8 cvt8(const float* p) {
  f32x4 a0 = *(const f32x4*)p;
  f32x4 a1 = *(const f32x4*)(p + 4);
  bf16x8 r;
#pragma unroll
  for (int j = 0; j < 4; ++j) { r[j] = (bf16)a0[j]; r[4 + j] = (bf16)a1[j]; }
  return r;
}

// ---------------------------------------------------------------------------
// prep_wt: write W in MFMA B-fragment order (unchanged).
// ---------------------------------------------------------------------------
__global__ void prep_wt(const float* __restrict__ Wq, const float* __restrict__ Wk,
                        const float* __restrict__ Wv, bf16* __restrict__ Wf) {
  int k = blockIdx.x;   // 0..255
  int c = threadIdx.x;  // 0..319
  float v;
  if (c < 32)       v = Wq[k * 32 + c];
  else if (c < 64)  v = Wk[k * 32 + (c - 32)];
  else              v = Wv[k * 256 + (c - 64)];
  int t5 = c >> 6, ct = (c >> 4) & 3, lwc = c & 15;
  int kc = k >> 5, qq = (k >> 3) & 3, ke = k & 7;
  Wf[((((t5 * 8 + kc) * 4 + ct) * 64) + qq * 16 + lwc) * 8 + ke] = (bf16)v;
}

// ---------------------------------------------------------------------------
// qkv_gemm: r5/r7-proven version (64-row tiles, 256 threads). r9 proved the
// occupancy rewrite is null — reverted to the simplest proven form.
// ---------------------------------------------------------------------------
__global__ __launch_bounds__(256) void qkv_gemm(
    const float* __restrict__ x, const bf16* __restrict__ Wf,
    const float* __restrict__ bq, const float* __restrict__ bk,
    const float* __restrict__ bv,
    bf16* __restrict__ Qd, bf16* __restrict__ Kd, bf16* __restrict__ Vt) {
  __shared__ __align__(16) bf16 tile[64 * 72];
  int tid = threadIdx.x;
  int lane = tid & 63, w = tid >> 6;
  int lw = lane & 15, qq = lane >> 4;
  int r0 = blockIdx.x * 64;
  int bb = r0 >> 12, n0 = r0 & 4095;

  const float* arow = x + (size_t)(r0 + 16 * w + lw) * 256;
  bf16x8 a[8];
#pragma unroll
  for (int kc = 0; kc < 8; ++kc) a[kc] = cvt8(arow + kc * 32 + qq * 8);

  for (int c0 = 0; c0 < 320; c0 += 64) {
    int t5 = c0 >> 6;
    f32x4 acc[4] = {};
#pragma unroll
    for (int kc = 0; kc < 8; ++kc)
#pragma unroll
      for (int t = 0; t < 4; ++t) {
        bf16x8 b = *(const bf16x8*)(Wf + ((size_t)(((t5 * 8 + kc) * 4 + t) * 64) + lane) * 8);
        acc[t] = mfma16(a[kc], b, acc[t]);
      }
    // C/D: col = lane&15, row = (lane>>4)*4 + i
    if (c0 == 0) {
#pragma unroll
      for (int t = 0; t < 4; ++t) {
        int c = 16 * t + lw;
        float bias = (c < 32) ? bq[c] : bk[c - 32];
#pragma unroll
        for (int i = 0; i < 4; ++i) {
          int n = n0 + 16 * w + 4 * qq + i;
          bf16 hv = (bf16)(acc[t][i] + bias);
          if (c < 32) Qd[((size_t)(bb << 12) + n) * 32 + c] = hv;
          else        Kd[((size_t)(bb << 12) + n) * 32 + (c - 32)] = hv;
        }
      }
    } else {
#pragma unroll
      for (int t = 0; t < 4; ++t) {
        int cl = 16 * t + lw;
        float bias = bv[c0 - 64 + cl];
#pragma unroll
        for (int i = 0; i < 4; ++i)
          tile[cl * 72 + 16 * w + 4 * qq + i] = (bf16)(acc[t][i] + bias);
      }
      __syncthreads();
      int nl = tid & 63;
#pragma unroll
      for (int it = 0; it < 16; ++it) {
        int cl = 4 * it + w;  // wave-uniform col -> 128B contiguous stores
        Vt[((size_t)bb * 256 + (c0 - 64) + cl) * 4096 + n0 + nl] = tile[cl * 72 + nl];
      }
      __syncthreads();
    }
  }
}

// ---------------------------------------------------------------------------
// flash_attn v10: r0 structure with (a) KVBLK 64->128 (32 phases instead of
// 64: per-phase fixed overhead — barrier, latency chains — amortized 2x) and
// (b) SWAPPED QK^T: s = mfma(K_frag, Q_frag) uses the SAME registers (A and
// B frags have identical per-lane layouts) and yields S^T with lane (qq,lw)
// holding S[kv=4qq+i][q=lw] — 4 CONTIGUOUS kv in the Pl[q][kv] layout -> P
// written as ONE ds_write_b64 per 16x16 subtile (vs 4 scalar b16). l becomes
// a single accumulator per lane (q=lw), reduced by 2 shfl_xor.
// P-reads (af), PV, V loads, o layout, epilogue: UNCHANGED from r0.
// Wave w: QK subtile rows(q) 16*(w&3), cols(kv) 64*(w>>2); PV ch [32w,+32).
// Pl stride 136 elems = 272B = 68 dwords ≡ 4 mod 32 banks — same conflict
// class as r0's proven 72-elem stride. LDS 35KB, 1 block/CU.
// ---------------------------------------------------------------------------
__global__ __launch_bounds__(512, 2) void flash_attn(
    const bf16* __restrict__ Qd, const bf16* __restrict__ Kd,
    const bf16* __restrict__ Vt, const float* __restrict__ x,
    const float* __restrict__ gamma, float* __restrict__ out) {
  __shared__ __align__(16) bf16 Pl[2][64 * 136];
  __shared__ __align__(16) float lsum2[2][64];

  int tid = threadIdx.x;
  int lane = tid & 63, w = tid >> 6;
  int lw = lane & 15, qq = lane >> 4;
  int wr = w & 3, wc = w >> 2, chb = 32 * w;
  int bb = blockIdx.y;
  int r0 = blockIdx.x * 64;

  const bf16* Qb = Qd + ((size_t)bb << 12) * 32;
  const bf16* Kb = Kd + ((size_t)bb << 12) * 32;
  const bf16* Vb = Vt + (size_t)bb * 256 * 4096;

  bf16x8 qf = *(const bf16x8*)(Qb + (size_t)(r0 + 16 * wr + lw) * 32 + qq * 8);

  f32x4 o[4][2] = {};
  float l_acc = 0.f;
  bf16x8 kbuf0[4], kbuf1[4], vbuf0[8], vbuf1[8];

  // ---- prologue: S(0) -> Pl[0]; prefetch K(1), V(0) ----
#pragma unroll
  for (int t = 0; t < 4; ++t)
    kbuf0[t] = *(const bf16x8*)(Kb + (size_t)(64 * wc + 16 * t + lw) * 32 + qq * 8);
#pragma unroll
  for (int t = 0; t < 4; ++t) {
    f32x4 z = {};
    f32x4 s = mfma16(kbuf0[t], qf, z);  // S^T: lane holds S[kv=4qq+i][q=lw]
    bf16x4 pk;
#pragma unroll
    for (int i = 0; i < 4; ++i) { float p = __expf(s[i]); l_acc += p; pk[i] = (bf16)p; }
    *(bf16x4*)&Pl[0][(16 * wr + lw) * 136 + 64 * wc + 16 * t + 4 * qq] = pk;
  }
#pragma unroll
  for (int t = 0; t < 4; ++t)
    kbuf1[t] = *(const bf16x8*)(Kb + (size_t)(128 + 64 * wc + 16 * t + lw) * 32 + qq * 8);
#pragma unroll
  for (int t = 0; t < 2; ++t)
#pragma unroll
    for (int kc = 0; kc < 4; ++kc)
      vbuf0[t * 4 + kc] = *(const bf16x8*)(Vb + (size_t)(chb + 16 * t + lw) * 4096 + kc * 32 + qq * 8);
  wg_barrier();

  // BODY(j, PCUR, PNXT, KN, KC, VC, VN): literal register-buffer names.
#define FA_BODY(J, PCUR, PNXT, KN, KC, VC, VN)                                     \
  {                                                                                \
    const int j = (J);                                                             \
    int n1 = ((j + 1) & 31) * 128, n2 = ((j + 2) & 31) * 128;                      \
    if (j < 31) {                                                                  \
      _Pragma("unroll") for (int t = 0; t < 4; ++t) {                              \
        f32x4 z = {};                                                              \
        f32x4 s = mfma16(KN[t], qf, z);                                            \
        bf16x4 pk;                                                                 \
        _Pragma("unroll") for (int i = 0; i < 4; ++i) {                            \
          float p = __expf(s[i]); l_acc += p; pk[i] = (bf16)p;                     \
        }                                                                          \
        *(bf16x4*)&Pl[PNXT][(16 * wr + lw) * 136 + 64 * wc + 16 * t + 4 * qq] = pk; \
      }                                                                            \
      _Pragma("unroll") for (int t = 0; t < 4; ++t)                                \
        KC[t] = *(const bf16x8*)(Kb + (size_t)(n2 + 64 * wc + 16 * t + lw) * 32 + qq * 8); \
    }                                                                              \
    _Pragma("unroll") for (int t = 0; t < 2; ++t)                                  \
      _Pragma("unroll") for (int kc = 0; kc < 4; ++kc)                             \
        VN[t * 4 + kc] = *(const bf16x8*)(Vb + (size_t)(chb + 16 * t + lw) * 4096 + n1 + kc * 32 + qq * 8); \
    _Pragma("unroll") for (int kc = 0; kc < 4; ++kc) {                             \
      bf16x8 afk[4];                                                               \
      _Pragma("unroll") for (int m = 0; m < 4; ++m)                                \
        afk[m] = *(const bf16x8*)&Pl[PCUR][(16 * m + lw) * 136 + kc * 32 + qq * 8]; \
      _Pragma("unroll") for (int t = 0; t < 2; ++t)                                \
        _Pragma("unroll") for (int m = 0; m < 4; ++m)                              \
          o[m][t] = mfma16(afk[m], VC[t * 4 + kc], o[m][t]);                       \
    }                                                                              \
    wg_barrier();                                                                  \
  }

  for (int jj = 0; jj < 16; ++jj) {
    FA_BODY(2 * jj,     0, 1, kbuf1, kbuf0, vbuf0, vbuf1)
    FA_BODY(2 * jj + 1, 1, 0, kbuf0, kbuf1, vbuf1, vbuf0)
  }
#undef FA_BODY

  // ---- l reduction: lane holds l for q=16wr+lw over kv-range of wc ----
  l_acc += __shfl_xor(l_acc, 16);
  l_acc += __shfl_xor(l_acc, 32);
  if (qq == 0) lsum2[wc][16 * wr + lw] = l_acc;
  __syncthreads();

  float g = gamma[0];
#pragma unroll
  for (int m = 0; m < 4; ++m) {
    f32x4 la = *(const f32x4*)&lsum2[0][16 * m + 4 * qq];
    f32x4 lb = *(const f32x4*)&lsum2[1][16 * m + 4 * qq];
#pragma unroll
    for (int i = 0; i < 4; ++i) {
      float rinv = 1.f / (la[i] + lb[i]);
      int row = r0 + 16 * m + 4 * qq + i;
      size_t base = (((size_t)bb << 12) + row) * 256 + chb;
#pragma unroll
      for (int t = 0; t < 2; ++t)
        out[base + 16 * t + lw] = g * (o[m][t][i] * rinv) + x[base + 16 * t + lw];
    }
  }
}

extern "C" void kernel_launch(void* const* d_in, const int* in_sizes, int n_in,
                              void* d_out, int out_size, void* d_ws, size_t ws_size,
                              hipStream_t stream) {
  const float* x     = (const float*)d_in[0];
  const float* Wq    = (const float*)d_in[1];
  const float* bq    = (const float*)d_in[2];
  const float* Wk    = (const float*)d_in[3];
  const float* bk    = (const float*)d_in[4];
  const float* Wv    = (const float*)d_in[5];
  const float* bv    = (const float*)d_in[6];
  const float* gamma = (const float*)d_in[7];
  float* out = (float*)d_out;

  const size_t WT_E = 320 * 256;
  const size_t QK_E = (size_t)4096 * 32;
  const size_t VT_E = (size_t)256 * 4096;
  size_t full_bytes = (WT_E + 4 * 2 * QK_E + 4 * VT_E) * sizeof(bf16);

  bf16* Wf = (bf16*)d_ws;
  prep_wt<<<dim3(256), dim3(320), 0, stream>>>(Wq, Wk, Wv, Wf);

  if (ws_size >= full_bytes) {
    bf16* Qd = Wf + WT_E;
    bf16* Kd = Qd + 4 * QK_E;
    bf16* Vt = Kd + 4 * QK_E;
    qkv_gemm<<<dim3(256), dim3(256), 0, stream>>>(x, Wf, bq, bk, bv, Qd, Kd, Vt);
    flash_attn<<<dim3(64, 4), dim3(512), 0, stream>>>(Qd, Kd, Vt, x, gamma, out);
  } else {
    bf16* Qd = Wf + WT_E;
    bf16* Kd = Qd + QK_E;
    bf16* Vt = Kd + QK_E;
    for (int b = 0; b < 4; ++b) {
      const float* xb = x + (size_t)b * 4096 * 256;
      float* outb = out + (size_t)b * 4096 * 256;
      qkv_gemm<<<dim3(64), dim3(256), 0, stream>>>(xb, Wf, bq, bk, bv, Qd, Kd, Vt);
      flash_attn<<<dim3(64, 1), dim3(512), 0, stream>>>(Qd, Kd, Vt, xb, gamma, outb);
    }
  }
}